// Round 2
// baseline (1200.426 us; speedup 1.0000x reference)
//
#include <hip/hip_runtime.h>
#include <cfloat>

// Problem constants (fixed by setup_inputs): B=64, S=2048, D=256, K=1024
#define DD 256
#define KK 1024
#define NROWS 131072            // B*S
#define QELEMS 33554432         // NROWS*DD
#define ROWS_PB 64              // rows per block in K1/K3
#define K1_THREADS 512          // 8 waves
#define GROUPS 8                // waves per block; each wave owns 16 codes/chunk
#define CPG 16                  // codes per thread per chunk
#define KCHUNK 128              // GROUPS*CPG
#define NCHUNK 8                // KK/KCHUNK

// ---------------------------------------------------------------------------
// k_rowsq: dst[r] = sum(src[r,:]^2) replicating numpy pairwise_sum bit-exactly
// for n=256: pw(a,256) = pw(a,128) + pw(a+128,128); pw(.,128) = 8 accumulators
// stride-8 (16 serial terms each), combined ((r0+r1)+(r2+r3))+((r4+r5)+(r6+r7)).
// One wave per row; lanes 0..15 hold (half, j) accumulators.
__global__ void k_rowsq(const float* __restrict__ src, float* __restrict__ dst,
                        int nrows) {
#pragma clang fp contract(off)
    const int lane = threadIdx.x & 63;
    const int wid = (blockIdx.x * blockDim.x + threadIdx.x) >> 6;  // wave-uniform
    if (wid >= nrows) return;
    float r = 0.0f;
    if (lane < 16) {
        const int half = lane >> 3, j = lane & 7;
        const float* a = src + (size_t)wid * DD + half * 128 + j;
        float v = a[0];
        r = v * v;                       // r[j] = a[j] (term, unfused)
        for (int t = 1; t < 16; ++t) {
            float u = a[8 * t];
            float p = u * u;             // rounded mul (flat*flat elementwise)
            r = r + p;                   // rounded add, numpy serial order
        }
    }
    // combine tree, preserving numpy's exact order (own-value-first adds)
    float o1 = __shfl_xor(r, 1); r = r + o1;   // (r0+r1), (r2+r3), ...
    float o2 = __shfl_xor(r, 2); r = r + o2;   // ((r0+r1)+(r2+r3)), ...
    float o4 = __shfl_xor(r, 4); r = r + o4;   // + ((r4+r5)+(r6+r7))
    float o8 = __shfl_xor(r, 8); r = r + o8;   // first128 + second128
    if (lane == 0) dst[wid] = r;
}

// ---------------------------------------------------------------------------
// k0_prep: transpose codebook -> ct[D][K]; zero hist / lossAcc.
__global__ void k0_prep(const float* __restrict__ cb, float* __restrict__ ct,
                        int* __restrict__ hist, float* __restrict__ lossAcc) {
    const int k = blockIdx.x, t = threadIdx.x;
    ct[t * KK + k] = cb[k * DD + t];
    if (k == 0) {
        for (int i = t; i < KK; i += 256) hist[i] = 0;
        if (t == 0) *lossAcc = 0.0f;
    }
}

// ---------------------------------------------------------------------------
// K1: argmin over np-f32-lattice distances. Each block: 64 rows x 1024 codes.
// row = tid&63 (lane), wave g = tid>>6 -> wave-uniform code addresses (s_load).
// dist[k] = fl( fl(x2 + c2[k]) - 2*dot ), dot = serial ascending-d fma chain
// (matches BLAS sgemm per-entry rounding). Strict < with ascending k ->
// np.argmin first-index tie semantics on identical bits.
__global__ __launch_bounds__(K1_THREADS, 4) void k1_argmin(
    const float* __restrict__ x, const float* __restrict__ ct,
    const float* __restrict__ c2, const float* __restrict__ x2,
    float* __restrict__ outIdx) {
    // xsT[d][row]: 256*64*4 = 64 KB; bank = row%32 -> 2-way (free)
    __shared__ float xsT[DD * ROWS_PB];

    const int tid = threadIdx.x;
    const int row0 = blockIdx.x * ROWS_PB;

    {   // stage 64 rows (row-major global) into transposed LDS
        const float4* xg = (const float4*)(x + (size_t)row0 * DD);
#pragma unroll
        for (int i = 0; i < (ROWS_PB * DD / 4) / K1_THREADS; ++i) {
            int lin = tid + i * K1_THREADS;   // 0..4095
            int r = lin >> 6;
            int c4 = lin & 63;
            float4 v = xg[lin];
            xsT[(c4 * 4 + 0) * ROWS_PB + r] = v.x;
            xsT[(c4 * 4 + 1) * ROWS_PB + r] = v.y;
            xsT[(c4 * 4 + 2) * ROWS_PB + r] = v.z;
            xsT[(c4 * 4 + 3) * ROWS_PB + r] = v.w;
        }
    }
    __syncthreads();

    const int row = tid & 63;
    const int g = __builtin_amdgcn_readfirstlane(tid >> 6);
    const float x2v = x2[row0 + row];

    float m1 = FLT_MAX;
    int bi = 0;

    for (int ch = 0; ch < NCHUNK; ++ch) {
        const int k0 = ch * KCHUNK + g * CPG;   // wave-uniform
        float acc[CPG];
#pragma unroll
        for (int j = 0; j < CPG; ++j) acc[j] = 0.0f;

#pragma unroll 4
        for (int d = 0; d < DD; ++d) {
            float xv = xsT[d * ROWS_PB + row];
            const float4* cp = (const float4*)(ct + d * KK + k0);  // uniform
            float4 c0 = cp[0], c1 = cp[1], c2v = cp[2], c3 = cp[3];
            acc[0]  = fmaf(xv, c0.x, acc[0]);
            acc[1]  = fmaf(xv, c0.y, acc[1]);
            acc[2]  = fmaf(xv, c0.z, acc[2]);
            acc[3]  = fmaf(xv, c0.w, acc[3]);
            acc[4]  = fmaf(xv, c1.x, acc[4]);
            acc[5]  = fmaf(xv, c1.y, acc[5]);
            acc[6]  = fmaf(xv, c1.z, acc[6]);
            acc[7]  = fmaf(xv, c1.w, acc[7]);
            acc[8]  = fmaf(xv, c2v.x, acc[8]);
            acc[9]  = fmaf(xv, c2v.y, acc[9]);
            acc[10] = fmaf(xv, c2v.z, acc[10]);
            acc[11] = fmaf(xv, c2v.w, acc[11]);
            acc[12] = fmaf(xv, c3.x, acc[12]);
            acc[13] = fmaf(xv, c3.y, acc[13]);
            acc[14] = fmaf(xv, c3.z, acc[14]);
            acc[15] = fmaf(xv, c3.w, acc[15]);
        }
#pragma unroll
        for (int j = 0; j < CPG; ++j) {
            float T1 = x2v + c2[k0 + j];        // rounded add (np broadcast add)
            float s = T1 - 2.0f * acc[j];       // 2*acc exact; one rounding
            if (s < m1) { m1 = s; bi = k0 + j; }  // ascending k: first-index ties
        }
    }

    // cross-wave merge (reuse xsT; all reads done)
    __syncthreads();
    float* rm1 = xsT;                 // [8][64]
    float* rmi = xsT + 512;           // [8][64] (int bits)
    rm1[g * 64 + row] = m1;
    rmi[g * 64 + row] = __int_as_float(bi);
    __syncthreads();

    if (tid < ROWS_PB) {
        float M1 = FLT_MAX;
        int BI = 0x7fffffff;
#pragma unroll
        for (int gg = 0; gg < GROUPS; ++gg) {
            float a1 = rm1[gg * 64 + tid];
            int ai = __float_as_int(rmi[gg * 64 + tid]);
            if (a1 < M1 || (a1 == M1 && ai < BI)) { M1 = a1; BI = ai; }
        }
        outIdx[row0 + tid] = (float)BI;
    }
}

// ---------------------------------------------------------------------------
// K3: gather quantized rows, accumulate loss sum and histogram.
__global__ __launch_bounds__(256) void k3_gather(
    const float* __restrict__ x, const float* __restrict__ cb,
    const float* __restrict__ outIdx, float* __restrict__ outQ,
    int* __restrict__ hist, float* __restrict__ lossAcc) {
    __shared__ int sidx[ROWS_PB];
    __shared__ float red[256];
    const int t = threadIdx.x;
    const int row0 = blockIdx.x * ROWS_PB;
    if (t < ROWS_PB) sidx[t] = (int)outIdx[row0 + t];
    __syncthreads();

    const float4* x4 = (const float4*)(x + (size_t)row0 * DD);
    float4* q4 = (float4*)(outQ + (size_t)row0 * DD);
    const float4* c4 = (const float4*)cb;
    float part = 0.0f;
#pragma unroll
    for (int i = 0; i < 16; ++i) {
        int lin = t + i * 256;
        int r = lin >> 6;
        int c = lin & 63;
        int k = sidx[r];
        float4 q = c4[(size_t)k * 64 + c];
        float4 xv = x4[lin];
        q4[lin] = q;
        float dx = q.x - xv.x, dy = q.y - xv.y, dz = q.z - xv.z, dw = q.w - xv.w;
        part += dx * dx + dy * dy + dz * dz + dw * dw;
        if ((t & 63) == 0) atomicAdd(hist + k, 1);
    }
    red[t] = part;
    __syncthreads();
    for (int s = 128; s > 0; s >>= 1) {
        if (t < s) red[t] += red[t + s];
        __syncthreads();
    }
    if (t == 0) atomicAdd(lossAcc, red[0]);
}

// ---------------------------------------------------------------------------
// K4: finalize loss + perplexity.
__global__ void k4_final(const int* __restrict__ hist,
                         const float* __restrict__ lossAcc,
                         float* __restrict__ outLoss,
                         float* __restrict__ outPerp) {
    __shared__ float red[256];
    const int t = threadIdx.x;
    float e = 0.0f;
    for (int i = t; i < KK; i += 256) {
        float p = (float)hist[i] * (1.0f / (float)NROWS);
        e -= p * logf(p + 1e-10f);
    }
    red[t] = e;
    __syncthreads();
    for (int s = 128; s > 0; s >>= 1) {
        if (t < s) red[t] += red[t + s];
        __syncthreads();
    }
    if (t == 0) {
        *outPerp = expf(red[0]);
        *outLoss = 1.25f * (*lossAcc) / (float)QELEMS;
    }
}

// ---------------------------------------------------------------------------
extern "C" void kernel_launch(void* const* d_in, const int* in_sizes, int n_in,
                              void* d_out, int out_size, void* d_ws, size_t ws_size,
                              hipStream_t stream) {
    const float* x = (const float*)d_in[0];    // [131072, 256]
    const float* cb = (const float*)d_in[1];   // [1024, 256]

    float* outQ = (float*)d_out;               // 33554432
    float* outIdx = outQ + QELEMS;             // 131072
    float* outLoss = outIdx + NROWS;           // 1
    float* outPerp = outLoss + 1;              // 1

    // ws layout (~1.5 MB)
    float* ct = (float*)d_ws;                  // [256][1024] = 1 MB
    float* c2 = ct + DD * KK;                  // 1024
    float* x2 = c2 + KK;                       // 131072
    int* hist = (int*)(x2 + NROWS);            // 1024
    float* lossAcc = (float*)(hist + KK);      // 1

    k_rowsq<<<dim3(NROWS / 4), dim3(256), 0, stream>>>(x, x2, NROWS);
    k_rowsq<<<dim3(KK / 4), dim3(256), 0, stream>>>(cb, c2, KK);
    k0_prep<<<dim3(KK), dim3(256), 0, stream>>>(cb, ct, hist, lossAcc);
    k1_argmin<<<dim3(NROWS / ROWS_PB), dim3(K1_THREADS), 0, stream>>>(
        x, ct, c2, x2, outIdx);
    k3_gather<<<dim3(NROWS / ROWS_PB), dim3(256), 0, stream>>>(
        x, cb, outIdx, outQ, hist, lossAcc);
    k4_final<<<dim3(1), dim3(256), 0, stream>>>(hist, lossAcc, outLoss, outPerp);
}

// Round 3
// 1046.729 us; speedup vs baseline: 1.1468x; 1.1468x over previous
//
#include <hip/hip_runtime.h>
#include <cfloat>

// Problem constants (fixed by setup_inputs): B=64, S=2048, D=256, K=1024
#define DD 256
#define KK 1024
#define NROWS 131072            // B*S
#define QELEMS 33554432         // NROWS*DD
#define ROWS_PB 64              // rows per block in K1
#define K1_THREADS 512          // 8 waves
#define GROUPS 8                // waves per block
#define CPG 32                  // codes per wave per chunk
#define NCHUNK 4                // KK / (GROUPS*CPG)
#define XSTRIDE 65              // padded LDS d-stride (kills 64-way staging conflicts)

// ---------------------------------------------------------------------------
// k_rowsq: dst[r] = sum(src[r,:]^2) replicating numpy pairwise_sum bit-exactly
// (n=256: two 128-halves, each 8 stride-8 accumulators of 16 serial terms,
// combined ((r0+r1)+(r2+r3))+((r4+r5)+(r6+r7)), halves added last).
// Used only for the codebook (1024 rows).
__global__ void k_rowsq(const float* __restrict__ src, float* __restrict__ dst,
                        int nrows) {
#pragma clang fp contract(off)
    const int lane = threadIdx.x & 63;
    const int wid = (blockIdx.x * blockDim.x + threadIdx.x) >> 6;
    if (wid >= nrows) return;
    float r = 0.0f;
    if (lane < 16) {
        const int half = lane >> 3, j = lane & 7;
        const float* a = src + (size_t)wid * DD + half * 128 + j;
        float v = a[0];
        r = v * v;
        for (int t = 1; t < 16; ++t) {
            float u = a[8 * t];
            float p = u * u;
            r = r + p;
        }
    }
    float o1 = __shfl_xor(r, 1); r = r + o1;
    float o2 = __shfl_xor(r, 2); r = r + o2;
    float o4 = __shfl_xor(r, 4); r = r + o4;
    float o8 = __shfl_xor(r, 8); r = r + o8;
    if (lane == 0) dst[wid] = r;
}

// ---------------------------------------------------------------------------
// k0_prep: transpose codebook -> ct[D][K]; zero hist / lossAcc.
__global__ void k0_prep(const float* __restrict__ cb, float* __restrict__ ct,
                        int* __restrict__ hist, float* __restrict__ lossAcc) {
    const int k = blockIdx.x, t = threadIdx.x;
    ct[t * KK + k] = cb[k * DD + t];
    if (k == 0) {
        for (int i = t; i < KK; i += 256) hist[i] = 0;
        if (t == 0) *lossAcc = 0.0f;
    }
}

// ---------------------------------------------------------------------------
// K1: fused argmin + x^2 + loss-sum + histogram.
// Block: 64 rows x 1024 codes. row = tid&63, wave g = tid>>6 (uniform) owns
// 32 codes per chunk -> wave-uniform ct addresses => s_load (SGPR broadcast).
// dist lattice matches numpy fp32 exactly: fl(fl(x2+c2) - 2*serial-fma-dot).
__global__ __launch_bounds__(K1_THREADS, 4) void k1_argmin(
    const float* __restrict__ x, const float* __restrict__ ct,
    const float* __restrict__ c2, float* __restrict__ outIdx,
    int* __restrict__ hist, float* __restrict__ lossAcc) {
    __shared__ float xsT[DD * XSTRIDE];   // xsT[d*65 + row], 66,560 B
    __shared__ float x2p[128];            // per-half pairwise partials

    const int tid = threadIdx.x;
    const int row0 = blockIdx.x * ROWS_PB;

    {   // stage 64 rows into transposed LDS (pad-65: writes 8-way, was 64-way)
        const float4* xg = (const float4*)(x + (size_t)row0 * DD);
#pragma unroll
        for (int i = 0; i < (ROWS_PB * DD / 4) / K1_THREADS; ++i) {
            int lin = tid + i * K1_THREADS;   // 0..4095
            int r = lin >> 6;
            int c4 = lin & 63;
            float4 v = xg[lin];
            xsT[(c4 * 4 + 0) * XSTRIDE + r] = v.x;
            xsT[(c4 * 4 + 1) * XSTRIDE + r] = v.y;
            xsT[(c4 * 4 + 2) * XSTRIDE + r] = v.z;
            xsT[(c4 * 4 + 3) * XSTRIDE + r] = v.w;
        }
    }
    __syncthreads();

    // x2 (np pairwise order, bit-exact), waves 0-1: one (row, half) per lane
    if (tid < 128) {
#pragma clang fp contract(off)
        const int r = tid & 63, half = tid >> 6;
        float a[8];
#pragma unroll
        for (int j = 0; j < 8; ++j) {
            float v = xsT[(half * 128 + j) * XSTRIDE + r];
            a[j] = v * v;
        }
#pragma unroll
        for (int t = 1; t < 16; ++t) {
#pragma unroll
            for (int j = 0; j < 8; ++j) {
                float u = xsT[(half * 128 + j + 8 * t) * XSTRIDE + r];
                float p = u * u;
                a[j] = a[j] + p;
            }
        }
        float s01 = a[0] + a[1], s23 = a[2] + a[3];
        float s45 = a[4] + a[5], s67 = a[6] + a[7];
        float sA = s01 + s23, sB = s45 + s67;
        x2p[half * 64 + r] = sA + sB;
    }
    __syncthreads();

    const int row = tid & 63;
    const int g = __builtin_amdgcn_readfirstlane(tid >> 6);
    const float x2v = x2p[row] + x2p[64 + row];   // pw(256)=pw128+pw128

    float m1 = FLT_MAX;
    int bi = 0;

    for (int ch = 0; ch < NCHUNK; ++ch) {
        const int k0 = ch * (GROUPS * CPG) + g * CPG;   // wave-uniform
        float acc[CPG];
#pragma unroll
        for (int j = 0; j < CPG; ++j) acc[j] = 0.0f;

#pragma unroll 2
        for (int d = 0; d < DD; ++d) {
            float xv = xsT[d * XSTRIDE + row];
            const float4* cp = (const float4*)(ct + d * KK + k0);  // uniform
            float4 q0 = cp[0], q1 = cp[1], q2 = cp[2], q3 = cp[3];
            float4 q4 = cp[4], q5 = cp[5], q6 = cp[6], q7 = cp[7];
            acc[0]  = fmaf(xv, q0.x, acc[0]);
            acc[1]  = fmaf(xv, q0.y, acc[1]);
            acc[2]  = fmaf(xv, q0.z, acc[2]);
            acc[3]  = fmaf(xv, q0.w, acc[3]);
            acc[4]  = fmaf(xv, q1.x, acc[4]);
            acc[5]  = fmaf(xv, q1.y, acc[5]);
            acc[6]  = fmaf(xv, q1.z, acc[6]);
            acc[7]  = fmaf(xv, q1.w, acc[7]);
            acc[8]  = fmaf(xv, q2.x, acc[8]);
            acc[9]  = fmaf(xv, q2.y, acc[9]);
            acc[10] = fmaf(xv, q2.z, acc[10]);
            acc[11] = fmaf(xv, q2.w, acc[11]);
            acc[12] = fmaf(xv, q3.x, acc[12]);
            acc[13] = fmaf(xv, q3.y, acc[13]);
            acc[14] = fmaf(xv, q3.z, acc[14]);
            acc[15] = fmaf(xv, q3.w, acc[15]);
            acc[16] = fmaf(xv, q4.x, acc[16]);
            acc[17] = fmaf(xv, q4.y, acc[17]);
            acc[18] = fmaf(xv, q4.z, acc[18]);
            acc[19] = fmaf(xv, q4.w, acc[19]);
            acc[20] = fmaf(xv, q5.x, acc[20]);
            acc[21] = fmaf(xv, q5.y, acc[21]);
            acc[22] = fmaf(xv, q5.z, acc[22]);
            acc[23] = fmaf(xv, q5.w, acc[23]);
            acc[24] = fmaf(xv, q6.x, acc[24]);
            acc[25] = fmaf(xv, q6.y, acc[25]);
            acc[26] = fmaf(xv, q6.z, acc[26]);
            acc[27] = fmaf(xv, q6.w, acc[27]);
            acc[28] = fmaf(xv, q7.x, acc[28]);
            acc[29] = fmaf(xv, q7.y, acc[29]);
            acc[30] = fmaf(xv, q7.z, acc[30]);
            acc[31] = fmaf(xv, q7.w, acc[31]);
        }
#pragma unroll
        for (int j = 0; j < CPG; ++j) {
            float T1 = x2v + c2[k0 + j];          // np broadcast add (rounded)
            float s = fmaf(-2.0f, acc[j], T1);    // fl(T1 - 2*dot)
            if (s < m1) { m1 = s; bi = k0 + j; }  // ascending k: first-index
        }
    }

    // cross-wave merge (reuse xsT; all reads done)
    __syncthreads();
    float* rm1 = xsT;                 // [8][64]
    float* rmi = xsT + 512;           // [8][64] (int bits)
    rm1[g * 64 + row] = m1;
    rmi[g * 64 + row] = __int_as_float(bi);
    __syncthreads();

    if (tid < ROWS_PB) {              // exactly wave 0
        float M1 = FLT_MAX;
        int BI = 0x7fffffff;
#pragma unroll
        for (int gg = 0; gg < GROUPS; ++gg) {
            float a1 = rm1[gg * 64 + tid];
            int ai = __float_as_int(rmi[gg * 64 + tid]);
            if (a1 < M1 || (a1 == M1 && ai < BI)) { M1 = a1; BI = ai; }
        }
        outIdx[row0 + tid] = (float)BI;
        atomicAdd(hist + BI, 1);
        // loss partial: sum of min squared distances over the block's rows
        float ls = M1;
#pragma unroll
        for (int off = 32; off > 0; off >>= 1) ls += __shfl_down(ls, off);
        if (tid == 0) atomicAdd(lossAcc, ls);
    }
}

// ---------------------------------------------------------------------------
// K3: pure gather -> outQ (x no longer read here).
__global__ __launch_bounds__(256) void k3_gather(
    const float* __restrict__ cb, const float* __restrict__ outIdx,
    float* __restrict__ outQ) {
    __shared__ int sidx[ROWS_PB];
    const int t = threadIdx.x;
    const int row0 = blockIdx.x * ROWS_PB;
    if (t < ROWS_PB) sidx[t] = (int)outIdx[row0 + t];
    __syncthreads();

    float4* q4 = (float4*)(outQ + (size_t)row0 * DD);
    const float4* c4 = (const float4*)cb;
#pragma unroll
    for (int i = 0; i < 16; ++i) {
        int lin = t + i * 256;
        int r = lin >> 6;
        int c = lin & 63;
        q4[lin] = c4[(size_t)sidx[r] * 64 + c];
    }
}

// ---------------------------------------------------------------------------
// K4: finalize loss + perplexity.
__global__ void k4_final(const int* __restrict__ hist,
                         const float* __restrict__ lossAcc,
                         float* __restrict__ outLoss,
                         float* __restrict__ outPerp) {
    __shared__ float red[256];
    const int t = threadIdx.x;
    float e = 0.0f;
    for (int i = t; i < KK; i += 256) {
        float p = (float)hist[i] * (1.0f / (float)NROWS);
        e -= p * logf(p + 1e-10f);
    }
    red[t] = e;
    __syncthreads();
    for (int s = 128; s > 0; s >>= 1) {
        if (t < s) red[t] += red[t + s];
        __syncthreads();
    }
    if (t == 0) {
        *outPerp = expf(red[0]);
        // loss = (1 + 0.25) * mean(min dist^2) ; lossAcc = sum over rows
        *outLoss = 1.25f * (*lossAcc) / (float)QELEMS;
    }
}

// ---------------------------------------------------------------------------
extern "C" void kernel_launch(void* const* d_in, const int* in_sizes, int n_in,
                              void* d_out, int out_size, void* d_ws, size_t ws_size,
                              hipStream_t stream) {
    const float* x = (const float*)d_in[0];    // [131072, 256]
    const float* cb = (const float*)d_in[1];   // [1024, 256]

    float* outQ = (float*)d_out;               // 33554432
    float* outIdx = outQ + QELEMS;             // 131072
    float* outLoss = outIdx + NROWS;           // 1
    float* outPerp = outLoss + 1;              // 1

    // ws layout (~1.1 MB)
    float* ct = (float*)d_ws;                  // [256][1024] = 1 MB
    float* c2 = ct + DD * KK;                  // 1024
    int* hist = (int*)(c2 + KK);               // 1024
    float* lossAcc = (float*)(hist + KK);      // 1

    k_rowsq<<<dim3(KK / 4), dim3(256), 0, stream>>>(cb, c2, KK);
    k0_prep<<<dim3(KK), dim3(256), 0, stream>>>(cb, ct, hist, lossAcc);
    k1_argmin<<<dim3(NROWS / ROWS_PB), dim3(K1_THREADS), 0, stream>>>(
        x, ct, c2, outIdx, hist, lossAcc);
    k3_gather<<<dim3(NROWS / ROWS_PB), dim3(256), 0, stream>>>(cb, outIdx, outQ);
    k4_final<<<dim3(1), dim3(256), 0, stream>>>(hist, lossAcc, outLoss, outPerp);
}